// Round 14
// baseline (570.229 us; speedup 1.0000x reference)
//
#include <hip/hip_runtime.h>
#include <hip/hip_bf16.h>

#define NN 50000
#define EE 800000
#define GG 64
#define LL 3
#define CC 4
#define HH 64
#define BN_EPS 1e-5f
#define NSHADOW 4
#define SBLK 196          // ceil(NN/256) node-parallel blocks
#define GIN_BLOCKS 2048   // grid-stride gather kernels (8192 waves)
#define MM_BLOCKS 256     // MFMA GEMM kernels (1024 waves >= 782 tiles)
#define ECHUNKS 3125      // ceil(EE/256)
#define NODE_RANGE 6250   // NN/8, dst-range binning for k_fill

// NOTE: harness passes ALL integer inputs as int32 (edge_index/batch included).
// NOTE: cooperative launch + grid.sync 4x SLOWER than kernel barriers (R5).
// NOTE: single-block k_final 90us latency-bound -> final MLP split (R7).
// NOTE: gather stays 1 node/wave, SEPARATE MLP kernels (R15/R17 fusion lost).
// NOTE: R11: GIN kernels are VALU-ISSUE bound; readlane broadcasts 745->646us.
// NOTE: R13: MLPs on MFMA 16x16x32 bf16: 654->563us.
//       Fragment layouts: A[m=lane&15][k=quad*8+j]; C/D[col=lane&15][row=quad*4+reg].
// NOTE: R16: 4-row vectorized gather neutral -> gather at random-access fabric
//       floor (~1.05TB/s, 12 x ~26us; neighbors uniform-random -> no locality).
//       fp8 rows inadmissible (absmax ~0.25 > 0.065).
// NOTE: R18/R26 (fused k_mlp thread, CLOSED): structural spin-skew = +55us vs
//       split; R22 all-RELAXED WRONG (stale local-L2 agent loads). Split final.
// NOTE: R25: 560.5us banked. k_fill was #1 dispatch: 45.7us, WRITE_SIZE 41.9MB
//       for 3.2MB payload (8-XCD 64B-line ping-pong on scattered stores).
// NOTE: R29: k_fill XCD-range pinning (range=blockIdx&7, round-robin dispatch
//       -> range r on XCD r, adj window L2-absorbed): 560.5 -> 548.8us,
//       k_fill out of top-5. CONFIRMED.
// NOTE: R30-R32 (resubmitted after timeouts): (1) k_deghist x-convert
//       vectorized float4->ushort4 (G13: hipcc won't auto-vectorize; 4 scalar
//       iters -> 1 vector iter); (2) t=2 pool fused into k_final1 (per-graph
//       range via binary search on sorted batch; pool xw rows coalesced; fold
//       into Wp1 product; k_pool launch + atomics + z[128:192) round-trip
//       deleted). Predict ~534-542us. Null -> remaining time is gather floor +
//       launch latency; stop shaving setup.

typedef __attribute__((ext_vector_type(8))) short bf16x8;
typedef __attribute__((ext_vector_type(4))) float f32x4;

__device__ __forceinline__ float bf2f(short s) {
    return __int_as_float(((int)(unsigned short)s) << 16);
}
__device__ __forceinline__ short f2bf(float v) {
    __hip_bfloat16 hb = __float2bfloat16(v);
    return *(short*)&hb;
}

// ---------------- setup kernels ----------------

// fused: x fp32->bf16 convert (float4 vectorized) + degree count + cluster
// histogram + W-fragment pack.
__global__ void k_deghist(const int* __restrict__ dst, int* __restrict__ deg,
                          const int* __restrict__ labels, int* __restrict__ blockcnt,
                          const float* __restrict__ x_in, __hip_bfloat16* __restrict__ xw,
                          const float* __restrict__ W1, const float* __restrict__ W2,
                          short* __restrict__ wf) {
    __shared__ int cnt[CC];
    int tid = threadIdx.x;
    // vectorized convert: NN*64/4 = 800000 float4s = exactly 3125*256 threads
    const float4* x4 = (const float4*)x_in;
    ushort4* xw4 = (ushort4*)xw;
    for (int i = blockIdx.x * 256 + tid; i < NN * 16; i += gridDim.x * 256) {
        float4 v = x4[i];
        ushort4 s;
        s.x = (unsigned short)f2bf(v.x);
        s.y = (unsigned short)f2bf(v.y);
        s.z = (unsigned short)f2bf(v.z);
        s.w = (unsigned short)f2bf(v.w);
        xw4[i] = s;
    }
    // W pack: first 384 blocks, one element per thread (24*4096 = 98304)
    int o = blockIdx.x * 256 + tid;
    if (o < 24 * 4096) {
        int m = o >> 12;
        int r = o & 4095;
        int colt = r >> 10;
        int fragk = (r >> 9) & 1;
        int lane = (r >> 3) & 63;
        int j = r & 7;
        int k = fragk * 32 + ((lane >> 4) << 3) + j;
        int n = colt * 16 + (lane & 15);
        const float* src = (m < 12) ? (W1 + (size_t)m * 4096) : (W2 + (size_t)(m - 12) * 4096);
        wf[o] = f2bf(src[k * 64 + n]);
    }
    bool hist = (blockIdx.x < SBLK);
    if (hist && tid < CC) cnt[tid] = 0;
    __syncthreads();
    int gid = blockIdx.x * 256 + tid;
    if (gid < EE) atomicAdd(&deg[dst[gid]], 1);
    if (hist && gid < NN) atomicAdd(&cnt[labels[gid]], 1);
    __syncthreads();
    if (hist && tid < CC) blockcnt[tid * SBLK + blockIdx.x] = cnt[tid];
}

__global__ __launch_bounds__(256) void k_scancombo(
    const int* __restrict__ deg, int* __restrict__ rowptr, int* __restrict__ dpart,
    const int* __restrict__ blockcnt, int* __restrict__ coffs, int* __restrict__ ccount) {
    __shared__ int smem[CC * 256];
    int tid = threadIdx.x;
    if (blockIdx.x < SBLK) {
        int i = blockIdx.x * 256 + tid;
        int v = (i < NN) ? deg[i] : 0;
        smem[tid] = v;
        __syncthreads();
        for (int off = 1; off < 256; off <<= 1) {
            int u = (tid >= off) ? smem[tid - off] : 0;
            __syncthreads();
            smem[tid] += u;
            __syncthreads();
        }
        if (i < NN) rowptr[i] = smem[tid] - v;  // local exclusive
        if (tid == 255) dpart[blockIdx.x] = smem[255];
    } else {
        int own[CC];
        for (int c = 0; c < CC; c++) {
            own[c] = (tid < SBLK) ? blockcnt[c * SBLK + tid] : 0;
            smem[c * 256 + tid] = own[c];
        }
        __syncthreads();
        for (int off = 1; off < 256; off <<= 1) {
            int v[CC];
            for (int c = 0; c < CC; c++) v[c] = (tid >= off) ? smem[c * 256 + tid - off] : 0;
            __syncthreads();
            for (int c = 0; c < CC; c++) smem[c * 256 + tid] += v[c];
            __syncthreads();
        }
        if (tid < SBLK)
            for (int c = 0; c < CC; c++) coffs[c * SBLK + tid] = smem[c * 256 + tid] - own[c];
        if (tid == 0)
            for (int c = 0; c < CC; c++) ccount[c] = smem[c * 256 + 255];
    }
}

__global__ __launch_bounds__(256) void k_dscan2(int* __restrict__ dpart,
                                                int* __restrict__ dbase,
                                                int* __restrict__ rowptr) {
    __shared__ int s[256];
    int tid = threadIdx.x;
    int v = (tid < SBLK) ? dpart[tid] : 0;
    s[tid] = v;
    __syncthreads();
    for (int off = 1; off < 256; off <<= 1) {
        int u = (tid >= off) ? s[tid - off] : 0;
        __syncthreads();
        s[tid] += u;
        __syncthreads();
    }
    if (tid < SBLK) dbase[tid] = s[tid] - v;
    if (tid == 0) rowptr[NN] = EE;
}

__global__ __launch_bounds__(256) void k_cfill_dscan3(
    int* __restrict__ rowptr, const int* __restrict__ dbase, int* __restrict__ cursor,
    const int* __restrict__ labels, const int* __restrict__ coffs, int* __restrict__ clist) {
    __shared__ int pos[CC];
    int tid = threadIdx.x;
    if (tid < CC) pos[tid] = coffs[tid * SBLK + blockIdx.x];
    __syncthreads();
    int i = blockIdx.x * 256 + tid;
    if (i < NN) {
        int r = rowptr[i] + dbase[blockIdx.x];
        rowptr[i] = r;
        cursor[i] = r;
        int c = labels[i];
        int p = atomicAdd(&pos[c], 1);
        clist[c * NN + p] = i;
    }
}

// RANGE-MAJOR binned CSR fill (R14) + XCD-range pinning (R27, confirmed R29).
// range = blockIdx&7: with round-robin block->XCD dispatch, all blocks of
// range r run on XCD r, so range r's ~400KB adj window stays in one L2.
// adj stores BYTE offsets: src<<7.
__global__ void k_fill(const int* __restrict__ src, const int* __restrict__ dst,
                       int* __restrict__ cursor, int* __restrict__ adj) {
    int range = blockIdx.x & 7;
    int e = (blockIdx.x >> 3) * 256 + threadIdx.x;
    if (e < EE) {
        int d = dst[e];
        int lo = range * NODE_RANGE;
        if (d >= lo && d < lo + NODE_RANGE) {
            int pos = atomicAdd(&cursor[d], 1);
            adj[pos] = src[e] << 7;
        }
    }
}

// ---------------- gather kernel (1 node/wave, 4 rows/issue, 8 chains) ----------------
// Lanes split into 4 groups of 16; each group loads a different neighbor row
// (16 lanes x 8B = 128B). Cross-group shfl_xor reduce at the end; group 0 writes.
// agg[idx] = x[node] + sum_{j->node} x[j]  (bf16 out).
// Optional fused pool of previous layer (tpool >= 0).
__global__ __launch_bounds__(256) void k_gather(
    const __hip_bfloat16* __restrict__ xw, const int* __restrict__ adj,
    const int* __restrict__ rowptr, const int* __restrict__ clist_c,
    const int* __restrict__ ccount_c, __hip_bfloat16* __restrict__ aggbuf,
    const int* __restrict__ batch, float* __restrict__ z, int tpool) {
    int cnt = *ccount_c;
    int lane = threadIdx.x & 63;
    int wave = threadIdx.x >> 6;
    int wid = blockIdx.x * 4 + wave;
    int nwaves = gridDim.x * 4;
    int grp = lane >> 4;   // 0..3: which row of the 4-row issue group
    int l16 = lane & 15;   // position within the 16-lane row loader
    const char* xwb = (const char*)xw;
    int idx = wid;
    int node_next = (idx < cnt) ? clist_c[idx] : 0;
    for (; idx < cnt; idx += nwaves) {
        int node = node_next;
        int nidx = idx + nwaves;
        if (nidx < cnt) node_next = clist_c[nidx];  // prefetch next node id
        int rb = rowptr[node], re = rowptr[node + 1];
        float ax[8], ay[8], az[8], aw[8];
        #pragma unroll
        for (int u = 0; u < 8; u++) { ax[u] = 0.f; ay[u] = 0.f; az[u] = 0.f; aw[u] = 0.f; }
        if (grp == 0) {  // self row: h = agg + x (summed in via cross-group reduce)
            uint2 v = *(const uint2*)(xwb + ((size_t)node << 7) + l16 * 8);
            ax[0] += __int_as_float((int)(v.x << 16));
            ay[0] += __int_as_float((int)(v.x & 0xffff0000u));
            az[0] += __int_as_float((int)(v.y << 16));
            aw[0] += __int_as_float((int)(v.y & 0xffff0000u));
        }
        int base = rb, rem = re - rb;
        while (rem > 0) {
            int take = min(rem, 64);
            int nb = adj[base + min(lane, take - 1)];  // byte offsets
            int j = 0;
            for (; j + 32 <= take; j += 32) {
                #pragma unroll
                for (int u = 0; u < 8; u++) {
                    int o = __shfl(nb, j + u * 4 + grp);
                    uint2 v = *(const uint2*)(xwb + o + l16 * 8);
                    ax[u] += __int_as_float((int)(v.x << 16));
                    ay[u] += __int_as_float((int)(v.x & 0xffff0000u));
                    az[u] += __int_as_float((int)(v.y << 16));
                    aw[u] += __int_as_float((int)(v.y & 0xffff0000u));
                }
            }
            for (; j + 16 <= take; j += 16) {
                #pragma unroll
                for (int u = 0; u < 4; u++) {
                    int o = __shfl(nb, j + u * 4 + grp);
                    uint2 v = *(const uint2*)(xwb + o + l16 * 8);
                    ax[u] += __int_as_float((int)(v.x << 16));
                    ay[u] += __int_as_float((int)(v.x & 0xffff0000u));
                    az[u] += __int_as_float((int)(v.y << 16));
                    aw[u] += __int_as_float((int)(v.y & 0xffff0000u));
                }
            }
            for (; j < take; j += 4) {
                int e = j + grp;
                int o = __shfl(nb, min(e, take - 1));
                if (e < take) {
                    uint2 v = *(const uint2*)(xwb + o + l16 * 8);
                    ax[0] += __int_as_float((int)(v.x << 16));
                    ay[0] += __int_as_float((int)(v.x & 0xffff0000u));
                    az[0] += __int_as_float((int)(v.y << 16));
                    aw[0] += __int_as_float((int)(v.y & 0xffff0000u));
                }
            }
            base += take; rem -= take;
        }
        float X = ((ax[0] + ax[1]) + (ax[2] + ax[3])) + ((ax[4] + ax[5]) + (ax[6] + ax[7]));
        float Y = ((ay[0] + ay[1]) + (ay[2] + ay[3])) + ((ay[4] + ay[5]) + (ay[6] + ay[7]));
        float Z = ((az[0] + az[1]) + (az[2] + az[3])) + ((az[4] + az[5]) + (az[6] + az[7]));
        float W = ((aw[0] + aw[1]) + (aw[2] + aw[3])) + ((aw[4] + aw[5]) + (aw[6] + aw[7]));
        X += __shfl_xor(X, 16); X += __shfl_xor(X, 32);
        Y += __shfl_xor(Y, 16); Y += __shfl_xor(Y, 32);
        Z += __shfl_xor(Z, 16); Z += __shfl_xor(Z, 32);
        W += __shfl_xor(W, 16); W += __shfl_xor(W, 32);
        if (grp == 0) {
            ushort4 st;
            st.x = (unsigned short)f2bf(X);
            st.y = (unsigned short)f2bf(Y);
            st.z = (unsigned short)f2bf(Z);
            st.w = (unsigned short)f2bf(W);
            *(ushort4*)((char*)aggbuf + ((size_t)idx << 7) + l16 * 8) = st;
        }
    }
    // -------- fused pool of previous layer (reads same xw state) --------
    if (tpool >= 0) {
        int lo = wid * 64;
        if (lo < NN) {
            int hi = min(lo + 64, NN);
            float acc = 0.f;
            int curg = batch[lo];
            for (int n = lo; n < hi; n++) {
                int g = batch[n];
                if (g != curg) {
                    atomicAdd(&z[curg * (HH * LL) + tpool * HH + lane], acc);
                    acc = 0.f;
                    curg = g;
                }
                acc += __bfloat162float(xw[(size_t)n * 64 + lane]);
            }
            atomicAdd(&z[curg * (HH * LL) + tpool * HH + lane], acc);
        }
    }
}

// ---------------- MFMA Lin1: h1 = agg @ W1 + b1 ; BN partials ----------------
__global__ __launch_bounds__(256) void k_lin1(
    const __hip_bfloat16* __restrict__ aggbuf, const int* __restrict__ ccount_c,
    const short* __restrict__ wf1, const float* __restrict__ b1c,
    __hip_bfloat16* __restrict__ h1buf, float* __restrict__ bnacc) {
    int cnt = *ccount_c;
    int tiles = (cnt + 15) >> 4;
    int lane = threadIdx.x & 63;
    int wave = threadIdx.x >> 6;
    int wid = blockIdx.x * 4 + wave;
    int nwaves = gridDim.x * 4;
    int quad = lane >> 4;
    int l15 = lane & 15;

    bf16x8 wb[8];
    #pragma unroll
    for (int f = 0; f < 8; f++)
        wb[f] = *(const bf16x8*)(wf1 + f * 512 + lane * 8);
    float bcol[4];
    #pragma unroll
    for (int colt = 0; colt < 4; colt++) bcol[colt] = b1c[colt * 16 + l15];

    float sS[4] = {0.f, 0.f, 0.f, 0.f};
    float sQ[4] = {0.f, 0.f, 0.f, 0.f};

    for (int tile = wid; tile < tiles; tile += nwaves) {
        int tb = tile << 4;
        int row = tb + l15;
        const __hip_bfloat16* ar = aggbuf + (size_t)row * 64 + quad * 8;
        bf16x8 a0 = *(const bf16x8*)ar;
        bf16x8 a1 = *(const bf16x8*)(ar + 32);
        #pragma unroll
        for (int colt = 0; colt < 4; colt++) {
            f32x4 acc = {0.f, 0.f, 0.f, 0.f};
            acc = __builtin_amdgcn_mfma_f32_16x16x32_bf16(a0, wb[colt * 2 + 0], acc, 0, 0, 0);
            acc = __builtin_amdgcn_mfma_f32_16x16x32_bf16(a1, wb[colt * 2 + 1], acc, 0, 0, 0);
            #pragma unroll
            for (int r = 0; r < 4; r++) {
                int nrow = tb + quad * 4 + r;
                if (nrow < cnt) {
                    float s = acc[r] + bcol[colt];
                    __hip_bfloat16 hb = __float2bfloat16(s);
                    h1buf[(size_t)nrow * 64 + colt * 16 + l15] = hb;
                    float st = __bfloat162float(hb);
                    sS[colt] += st;
                    sQ[colt] += st * st;
                }
            }
        }
    }
    // reduce across quads (cols replicated in lanes l15, +16, +32, +48)
    #pragma unroll
    for (int colt = 0; colt < 4; colt++) {
        sS[colt] += __shfl_xor(sS[colt], 16); sS[colt] += __shfl_xor(sS[colt], 32);
        sQ[colt] += __shfl_xor(sQ[colt], 16); sQ[colt] += __shfl_xor(sQ[colt], 32);
    }
    if (quad == 0) {
        int slot = (blockIdx.x & (NSHADOW - 1)) * 128;
        #pragma unroll
        for (int colt = 0; colt < 4; colt++) {
            atomicAdd(&bnacc[slot + colt * 16 + l15], sS[colt]);
            atomicAdd(&bnacc[slot + 64 + colt * 16 + l15], sQ[colt]);
        }
    }
}

// ---------------- MFMA C: xw[node] = relu(bn(h1)) @ W2 + b2 ----------------
__global__ __launch_bounds__(256) void k_cmfma(
    __hip_bfloat16* __restrict__ xw, const int* __restrict__ clist_c,
    const int* __restrict__ ccount_c, const float* __restrict__ g1c,
    const float* __restrict__ be1c, const short* __restrict__ wf2,
    const float* __restrict__ b2c, const __hip_bfloat16* __restrict__ h1buf,
    const float* __restrict__ bnacc) {
    __shared__ float lds_scale[64];
    __shared__ float lds_shift[64];
    int cnt = *ccount_c;
    int tiles = (cnt + 15) >> 4;
    int lane = threadIdx.x & 63;
    int wave = threadIdx.x >> 6;
    int wid = blockIdx.x * 4 + wave;
    int nwaves = gridDim.x * 4;
    int quad = lane >> 4;
    int l15 = lane & 15;

    if (threadIdx.x < 64) {
        float s = 0.f, q = 0.f;
        #pragma unroll
        for (int sh = 0; sh < NSHADOW; sh++) {
            s += bnacc[sh * 128 + threadIdx.x];
            q += bnacc[sh * 128 + 64 + threadIdx.x];
        }
        float fc = fmaxf((float)cnt, 1.f);
        float mean = s / fc;
        float var = q / fc - mean * mean;
        float sc = g1c[threadIdx.x] * rsqrtf(var + BN_EPS);
        lds_scale[threadIdx.x] = sc;
        lds_shift[threadIdx.x] = be1c[threadIdx.x] - mean * sc;
    }
    __syncthreads();

    bf16x8 wb[8];
    #pragma unroll
    for (int f = 0; f < 8; f++)
        wb[f] = *(const bf16x8*)(wf2 + f * 512 + lane * 8);
    float bcol[4];
    #pragma unroll
    for (int colt = 0; colt < 4; colt++) bcol[colt] = b2c[colt * 16 + l15];
    float scl0[8], sft0[8], scl1[8], sft1[8];
    #pragma unroll
    for (int j = 0; j < 8; j++) {
        int ch = quad * 8 + j;
        scl0[j] = lds_scale[ch];      sft0[j] = lds_shift[ch];
        scl1[j] = lds_scale[ch + 32]; sft1[j] = lds_shift[ch + 32];
    }

    for (int tile = wid; tile < tiles; tile += nwaves) {
        int tb = tile << 4;
        int row = tb + l15;
        const __hip_bfloat16* hr = h1buf + (size_t)row * 64 + quad * 8;
        bf16x8 h0 = *(const bf16x8*)hr;
        bf16x8 h1f = *(const bf16x8*)(hr + 32);
        bf16x8 a0, a1;
        #pragma unroll
        for (int j = 0; j < 8; j++) {
            a0[j] = f2bf(fmaxf(bf2f(h0[j]) * scl0[j] + sft0[j], 0.f));
            a1[j] = f2bf(fmaxf(bf2f(h1f[j]) * scl1[j] + sft1[j], 0.f));
        }
        #pragma unroll
        for (int colt = 0; colt < 4; colt++) {
            f32x4 acc = {0.f, 0.f, 0.f, 0.f};
            acc = __builtin_amdgcn_mfma_f32_16x16x32_bf16(a0, wb[colt * 2 + 0], acc, 0, 0, 0);
            acc = __builtin_amdgcn_mfma_f32_16x16x32_bf16(a1, wb[colt * 2 + 1], acc, 0, 0, 0);
            #pragma unroll
            for (int r = 0; r < 4; r++) {
                int nrow = tb + quad * 4 + r;
                if (nrow < cnt) {
                    int node = clist_c[nrow];
                    xw[(size_t)node * 64 + colt * 16 + l15] =
                        __float2bfloat16(acc[r] + bcol[colt]);
                }
            }
        }
    }
}

// ---------------- final MLP stage 1 (+fused t=2 pool, R30) ----------------
// Block g: binary-search graph g's node range in sorted batch, pool xw rows
// (t=2 state) into LDS, then hbuf[g] = z[g,0:128]@Wp1[0:128] + pool@Wp1[128:192] + bp1.
__global__ __launch_bounds__(256) void k_final1(
    const float* __restrict__ z, const __hip_bfloat16* __restrict__ xw,
    const int* __restrict__ batch, const float* __restrict__ Wp1,
    const float* __restrict__ bp1, float* __restrict__ hbuf) {
    __shared__ float red[256];
    __shared__ float pool2[64];
    int g = blockIdx.x;
    int k = threadIdx.x & 63;
    int part = threadIdx.x >> 6;  // 4 parts
    // per-graph node range [lo, hi): lower_bound(g), lower_bound(g+1)
    int lo, hi;
    {
        int a = 0, b = NN;
        while (a < b) { int m = (a + b) >> 1; if (batch[m] < g) a = m + 1; else b = m; }
        lo = a;
        b = NN;
        while (a < b) { int m = (a + b) >> 1; if (batch[m] < g + 1) a = m + 1; else b = m; }
        hi = a;
    }
    // pool t=2 state: thread (part,k) sums channel k of nodes lo+part, lo+part+4, ...
    float pacc = 0.f;
    for (int n = lo + part; n < hi; n += 4)
        pacc += __bfloat162float(xw[(size_t)n * 64 + k]);
    red[threadIdx.x] = pacc;
    __syncthreads();
    if (part == 0) pool2[k] = red[k] + red[64 + k] + red[128 + k] + red[192 + k];
    __syncthreads();
    // z part (j in [0,128), split 4x32) + pooled part (c2 in [128,192), split 4x16)
    float s = 0.f;
    #pragma unroll 8
    for (int j = part * 32; j < (part + 1) * 32; j++)
        s += z[g * (HH * LL) + j] * Wp1[j * 64 + k];
    #pragma unroll 4
    for (int c2 = part * 16; c2 < (part + 1) * 16; c2++)
        s += pool2[c2] * Wp1[(128 + c2) * 64 + k];
    __syncthreads();
    red[threadIdx.x] = s;
    __syncthreads();
    if (part == 0)
        hbuf[g * 64 + k] = red[k] + red[64 + k] + red[128 + k] + red[192 + k] + bp1[k];
}

__global__ __launch_bounds__(256) void k_final2(
    const float* __restrict__ hbuf, const float* __restrict__ gp,
    const float* __restrict__ bep, const float* __restrict__ Wp2,
    const float* __restrict__ bp2, float* __restrict__ out) {
    __shared__ float lds[64 * 64];
    __shared__ float sscale[64];
    __shared__ float sshift[64];
    int tid = threadIdx.x;
    for (int i = tid; i < 64 * 64; i += 256) lds[i] = hbuf[i];
    __syncthreads();
    if (tid < 64) {
        float s = 0.f, q = 0.f;
        for (int g = 0; g < 64; g++) { float v = lds[g * 64 + tid]; s += v; q += v * v; }
        float mean = s / 64.f;
        float var = q / 64.f - mean * mean;
        float sc = gp[tid] * rsqrtf(var + BN_EPS);
        sscale[tid] = sc;
        sshift[tid] = bep[tid] - mean * sc;
    }
    __syncthreads();
    for (int i = tid; i < 64 * 64; i += 256) {
        int k = i & 63;
        lds[i] = fmaxf(lds[i] * sscale[k] + sshift[k], 0.f);
    }
    __syncthreads();
    for (int i = tid; i < 64 * 64; i += 256) {
        int g = i >> 6, o = i & 63;
        float s = bp2[o];
        #pragma unroll 8
        for (int k = 0; k < 64; k++) s += lds[g * 64 + k] * Wp2[k * 64 + o];
        out[g * 64 + o] = s;
    }
}

// ---------------- launch ----------------
extern "C" void kernel_launch(void* const* d_in, const int* in_sizes, int n_in,
                              void* d_out, int out_size, void* d_ws, size_t ws_size,
                              hipStream_t stream) {
    const float* x_in = (const float*)d_in[0];
    const int* labels = (const int*)d_in[1];
    const int* esrc = (const int*)d_in[2];
    const int* edst = esrc + EE;
    const int* batch = (const int*)d_in[3];
    const float* W1 = (const float*)d_in[4];
    const float* b1 = (const float*)d_in[5];
    const float* g1 = (const float*)d_in[6];
    const float* be1 = (const float*)d_in[7];
    const float* W2 = (const float*)d_in[8];
    const float* b2 = (const float*)d_in[9];
    const float* Wp1 = (const float*)d_in[10];
    const float* bp1 = (const float*)d_in[11];
    const float* gp = (const float*)d_in[12];
    const float* bep = (const float*)d_in[13];
    const float* Wp2 = (const float*)d_in[14];
    const float* bp2 = (const float*)d_in[15];
    float* out = (float*)d_out;

    char* p = (char*)d_ws;
    auto carve = [&](size_t bytes) -> void* {
        void* r = (void*)p;
        p += (bytes + 255) & ~(size_t)255;
        return r;
    };
    // ---- zeroed region (one memset) ----
    float* bnacc = (float*)carve((size_t)LL * CC * NSHADOW * 128 * 4);
    float* z     = (float*)carve((size_t)GG * HH * LL * 4);
    int*   deg   = (int*)carve((size_t)NN * 4);
    size_t zero_bytes = (size_t)(p - (char*)d_ws);
    // ---- rest ----
    int*   ccount  = (int*)carve(CC * 4);
    int*   blockcnt= (int*)carve((size_t)CC * SBLK * 4);
    int*   coffs   = (int*)carve((size_t)CC * SBLK * 4);
    int*   dpart   = (int*)carve((size_t)SBLK * 4);
    int*   dbase   = (int*)carve((size_t)SBLK * 4);
    __hip_bfloat16* xw     = (__hip_bfloat16*)carve((size_t)NN * 64 * 2);
    __hip_bfloat16* aggbuf = (__hip_bfloat16*)carve((size_t)NN * 64 * 2);
    __hip_bfloat16* h1buf  = (__hip_bfloat16*)carve((size_t)NN * 64 * 2);
    short* wf      = (short*)carve((size_t)24 * 4096 * 2);
    float* hbuf    = (float*)carve((size_t)GG * 64 * 4);
    int*   rowptr  = (int*)carve((size_t)(NN + 1) * 4);
    int*   cursor  = (int*)carve((size_t)NN * 4);
    int*   adj     = (int*)carve((size_t)EE * 4);
    int*   clist   = (int*)carve((size_t)CC * NN * 4);

    hipMemsetAsync(d_ws, 0, zero_bytes, stream);

    k_deghist<<<ECHUNKS, 256, 0, stream>>>(edst, deg, labels, blockcnt, x_in, xw, W1, W2, wf);
    k_scancombo<<<SBLK + 1, 256, 0, stream>>>(deg, rowptr, dpart, blockcnt, coffs, ccount);
    k_dscan2<<<1, 256, 0, stream>>>(dpart, dbase, rowptr);
    k_cfill_dscan3<<<SBLK, 256, 0, stream>>>(rowptr, dbase, cursor, labels, coffs, clist);
    k_fill<<<ECHUNKS * 8, 256, 0, stream>>>(esrc, edst, cursor, adj);

    for (int t = 0; t < LL; t++) {
        for (int c = 0; c < CC; c++) {
            int tc = t * CC + c;
            int tpool = (c == 0) ? (t - 1) : -1;  // fuse previous layer's pool into gather
            k_gather<<<GIN_BLOCKS, 256, 0, stream>>>(
                xw, adj, rowptr, clist + c * NN, ccount + c, aggbuf, batch, z, tpool);
            k_lin1<<<MM_BLOCKS, 256, 0, stream>>>(
                aggbuf, ccount + c, wf + (size_t)tc * 4096, b1 + (size_t)tc * 64,
                h1buf, bnacc + (size_t)tc * NSHADOW * 128);
            k_cmfma<<<MM_BLOCKS, 256, 0, stream>>>(
                xw, clist + c * NN, ccount + c,
                g1 + (size_t)tc * 64, be1 + (size_t)tc * 64,
                wf + (size_t)(12 + tc) * 4096, b2 + (size_t)tc * 64,
                h1buf, bnacc + (size_t)tc * NSHADOW * 128);
        }
    }
    // t=2 pool is fused into k_final1 (R30); no standalone k_pool.
    k_final1<<<GG, 256, 0, stream>>>(z, xw, batch, Wp1, bp1, hbuf);
    k_final2<<<1, 256, 0, stream>>>(hbuf, gp, bep, Wp2, bp2, out);
}

// Round 15
// 547.364 us; speedup vs baseline: 1.0418x; 1.0418x over previous
//
#include <hip/hip_runtime.h>
#include <hip/hip_bf16.h>

#define NN 50000
#define EE 800000
#define GG 64
#define LL 3
#define CC 4
#define HH 64
#define BN_EPS 1e-5f
#define NSHADOW 4
#define SBLK 196          // ceil(NN/256) node-parallel blocks
#define GIN_BLOCKS 2048   // grid-stride gather kernels (8192 waves)
#define MM_BLOCKS 256     // MFMA GEMM kernels (1024 waves >= 782 tiles)
#define ECHUNKS 3125      // ceil(EE/256)
#define NODE_RANGE 6250   // NN/8, dst-range binning for k_fill

// NOTE: harness passes ALL integer inputs as int32 (edge_index/batch included).
// NOTE: cooperative launch + grid.sync 4x SLOWER than kernel barriers (R5).
// NOTE: single-block k_final 90us latency-bound -> final MLP split (R7).
// NOTE: gather stays 1 node/wave, SEPARATE MLP kernels (R15/R17 fusion lost).
// NOTE: R11: GIN kernels are VALU-ISSUE bound; readlane broadcasts 745->646us.
// NOTE: R13: MLPs on MFMA 16x16x32 bf16: 654->563us.
//       Fragment layouts: A[m=lane&15][k=quad*8+j]; C/D[col=lane&15][row=quad*4+reg].
// NOTE: R16: 4-row vectorized gather neutral -> gather at random-access fabric
//       floor (~1.05TB/s, 12 x ~26us; neighbors uniform-random -> no locality).
//       fp8 rows inadmissible (absmax ~0.25 > 0.065).
// NOTE: R18/R26 (fused k_mlp thread, CLOSED): structural spin-skew = +55us vs
//       split; R22 all-RELAXED WRONG (stale local-L2 agent loads). Split final.
// NOTE: R25: 560.5us banked. R29: k_fill XCD-range pinning (range=blockIdx&7):
//       560.5 -> 548.8us, k_fill (45.7us, 41.9MB WRITE) out of top-5. CONFIRMED.
// NOTE: R33 (=R30 measured): t=2 pool fused into 64-block k_final1 REGRESSED
//       548.8 -> 570.2us; k_final1 became top dispatch 57.7us @2.4% occupancy,
//       0.76% HBM (6.4MB xw read on 64 blocks = latency-bound serial pool).
//       LESSON: never shrink the grid below CU count to save a launch.
//       REVERTED this round: standalone 196-block k_pool + z-based k_final1
//       restored. KEPT: k_deghist float4->ushort4 convert (G13; exonerated by
//       counters - R30's regression was fully k_final1).
//       Predict ~541-547us; >=549 -> deghist vec neutral, structure at floor
//       (gather fabric floor ~310us + launch overhead is the defended budget).

typedef __attribute__((ext_vector_type(8))) short bf16x8;
typedef __attribute__((ext_vector_type(4))) float f32x4;

__device__ __forceinline__ float bf2f(short s) {
    return __int_as_float(((int)(unsigned short)s) << 16);
}
__device__ __forceinline__ short f2bf(float v) {
    __hip_bfloat16 hb = __float2bfloat16(v);
    return *(short*)&hb;
}

// ---------------- setup kernels ----------------

// fused: x fp32->bf16 convert (float4 vectorized, R30-kept) + degree count +
// cluster histogram + W-fragment pack.
__global__ void k_deghist(const int* __restrict__ dst, int* __restrict__ deg,
                          const int* __restrict__ labels, int* __restrict__ blockcnt,
                          const float* __restrict__ x_in, __hip_bfloat16* __restrict__ xw,
                          const float* __restrict__ W1, const float* __restrict__ W2,
                          short* __restrict__ wf) {
    __shared__ int cnt[CC];
    int tid = threadIdx.x;
    // vectorized convert: NN*64/4 = 800000 float4s = exactly 3125*256 threads
    const float4* x4 = (const float4*)x_in;
    ushort4* xw4 = (ushort4*)xw;
    for (int i = blockIdx.x * 256 + tid; i < NN * 16; i += gridDim.x * 256) {
        float4 v = x4[i];
        ushort4 s;
        s.x = (unsigned short)f2bf(v.x);
        s.y = (unsigned short)f2bf(v.y);
        s.z = (unsigned short)f2bf(v.z);
        s.w = (unsigned short)f2bf(v.w);
        xw4[i] = s;
    }
    // W pack: first 384 blocks, one element per thread (24*4096 = 98304)
    int o = blockIdx.x * 256 + tid;
    if (o < 24 * 4096) {
        int m = o >> 12;
        int r = o & 4095;
        int colt = r >> 10;
        int fragk = (r >> 9) & 1;
        int lane = (r >> 3) & 63;
        int j = r & 7;
        int k = fragk * 32 + ((lane >> 4) << 3) + j;
        int n = colt * 16 + (lane & 15);
        const float* src = (m < 12) ? (W1 + (size_t)m * 4096) : (W2 + (size_t)(m - 12) * 4096);
        wf[o] = f2bf(src[k * 64 + n]);
    }
    bool hist = (blockIdx.x < SBLK);
    if (hist && tid < CC) cnt[tid] = 0;
    __syncthreads();
    int gid = blockIdx.x * 256 + tid;
    if (gid < EE) atomicAdd(&deg[dst[gid]], 1);
    if (hist && gid < NN) atomicAdd(&cnt[labels[gid]], 1);
    __syncthreads();
    if (hist && tid < CC) blockcnt[tid * SBLK + blockIdx.x] = cnt[tid];
}

__global__ __launch_bounds__(256) void k_scancombo(
    const int* __restrict__ deg, int* __restrict__ rowptr, int* __restrict__ dpart,
    const int* __restrict__ blockcnt, int* __restrict__ coffs, int* __restrict__ ccount) {
    __shared__ int smem[CC * 256];
    int tid = threadIdx.x;
    if (blockIdx.x < SBLK) {
        int i = blockIdx.x * 256 + tid;
        int v = (i < NN) ? deg[i] : 0;
        smem[tid] = v;
        __syncthreads();
        for (int off = 1; off < 256; off <<= 1) {
            int u = (tid >= off) ? smem[tid - off] : 0;
            __syncthreads();
            smem[tid] += u;
            __syncthreads();
        }
        if (i < NN) rowptr[i] = smem[tid] - v;  // local exclusive
        if (tid == 255) dpart[blockIdx.x] = smem[255];
    } else {
        int own[CC];
        for (int c = 0; c < CC; c++) {
            own[c] = (tid < SBLK) ? blockcnt[c * SBLK + tid] : 0;
            smem[c * 256 + tid] = own[c];
        }
        __syncthreads();
        for (int off = 1; off < 256; off <<= 1) {
            int v[CC];
            for (int c = 0; c < CC; c++) v[c] = (tid >= off) ? smem[c * 256 + tid - off] : 0;
            __syncthreads();
            for (int c = 0; c < CC; c++) smem[c * 256 + tid] += v[c];
            __syncthreads();
        }
        if (tid < SBLK)
            for (int c = 0; c < CC; c++) coffs[c * SBLK + tid] = smem[c * 256 + tid] - own[c];
        if (tid == 0)
            for (int c = 0; c < CC; c++) ccount[c] = smem[c * 256 + 255];
    }
}

__global__ __launch_bounds__(256) void k_dscan2(int* __restrict__ dpart,
                                                int* __restrict__ dbase,
                                                int* __restrict__ rowptr) {
    __shared__ int s[256];
    int tid = threadIdx.x;
    int v = (tid < SBLK) ? dpart[tid] : 0;
    s[tid] = v;
    __syncthreads();
    for (int off = 1; off < 256; off <<= 1) {
        int u = (tid >= off) ? s[tid - off] : 0;
        __syncthreads();
        s[tid] += u;
        __syncthreads();
    }
    if (tid < SBLK) dbase[tid] = s[tid] - v;
    if (tid == 0) rowptr[NN] = EE;
}

__global__ __launch_bounds__(256) void k_cfill_dscan3(
    int* __restrict__ rowptr, const int* __restrict__ dbase, int* __restrict__ cursor,
    const int* __restrict__ labels, const int* __restrict__ coffs, int* __restrict__ clist) {
    __shared__ int pos[CC];
    int tid = threadIdx.x;
    if (tid < CC) pos[tid] = coffs[tid * SBLK + blockIdx.x];
    __syncthreads();
    int i = blockIdx.x * 256 + tid;
    if (i < NN) {
        int r = rowptr[i] + dbase[blockIdx.x];
        rowptr[i] = r;
        cursor[i] = r;
        int c = labels[i];
        int p = atomicAdd(&pos[c], 1);
        clist[c * NN + p] = i;
    }
}

// RANGE-MAJOR binned CSR fill (R14) + XCD-range pinning (R27, confirmed R29).
// range = blockIdx&7: with round-robin block->XCD dispatch, all blocks of
// range r run on XCD r, so range r's ~400KB adj window stays in one L2.
// adj stores BYTE offsets: src<<7.
__global__ void k_fill(const int* __restrict__ src, const int* __restrict__ dst,
                       int* __restrict__ cursor, int* __restrict__ adj) {
    int range = blockIdx.x & 7;
    int e = (blockIdx.x >> 3) * 256 + threadIdx.x;
    if (e < EE) {
        int d = dst[e];
        int lo = range * NODE_RANGE;
        if (d >= lo && d < lo + NODE_RANGE) {
            int pos = atomicAdd(&cursor[d], 1);
            adj[pos] = src[e] << 7;
        }
    }
}

// ---------------- gather kernel (1 node/wave, 4 rows/issue, 8 chains) ----------------
// Lanes split into 4 groups of 16; each group loads a different neighbor row
// (16 lanes x 8B = 128B). Cross-group shfl_xor reduce at the end; group 0 writes.
// agg[idx] = x[node] + sum_{j->node} x[j]  (bf16 out).
// Optional fused pool of previous layer (tpool >= 0).
__global__ __launch_bounds__(256) void k_gather(
    const __hip_bfloat16* __restrict__ xw, const int* __restrict__ adj,
    const int* __restrict__ rowptr, const int* __restrict__ clist_c,
    const int* __restrict__ ccount_c, __hip_bfloat16* __restrict__ aggbuf,
    const int* __restrict__ batch, float* __restrict__ z, int tpool) {
    int cnt = *ccount_c;
    int lane = threadIdx.x & 63;
    int wave = threadIdx.x >> 6;
    int wid = blockIdx.x * 4 + wave;
    int nwaves = gridDim.x * 4;
    int grp = lane >> 4;   // 0..3: which row of the 4-row issue group
    int l16 = lane & 15;   // position within the 16-lane row loader
    const char* xwb = (const char*)xw;
    int idx = wid;
    int node_next = (idx < cnt) ? clist_c[idx] : 0;
    for (; idx < cnt; idx += nwaves) {
        int node = node_next;
        int nidx = idx + nwaves;
        if (nidx < cnt) node_next = clist_c[nidx];  // prefetch next node id
        int rb = rowptr[node], re = rowptr[node + 1];
        float ax[8], ay[8], az[8], aw[8];
        #pragma unroll
        for (int u = 0; u < 8; u++) { ax[u] = 0.f; ay[u] = 0.f; az[u] = 0.f; aw[u] = 0.f; }
        if (grp == 0) {  // self row: h = agg + x (summed in via cross-group reduce)
            uint2 v = *(const uint2*)(xwb + ((size_t)node << 7) + l16 * 8);
            ax[0] += __int_as_float((int)(v.x << 16));
            ay[0] += __int_as_float((int)(v.x & 0xffff0000u));
            az[0] += __int_as_float((int)(v.y << 16));
            aw[0] += __int_as_float((int)(v.y & 0xffff0000u));
        }
        int base = rb, rem = re - rb;
        while (rem > 0) {
            int take = min(rem, 64);
            int nb = adj[base + min(lane, take - 1)];  // byte offsets
            int j = 0;
            for (; j + 32 <= take; j += 32) {
                #pragma unroll
                for (int u = 0; u < 8; u++) {
                    int o = __shfl(nb, j + u * 4 + grp);
                    uint2 v = *(const uint2*)(xwb + o + l16 * 8);
                    ax[u] += __int_as_float((int)(v.x << 16));
                    ay[u] += __int_as_float((int)(v.x & 0xffff0000u));
                    az[u] += __int_as_float((int)(v.y << 16));
                    aw[u] += __int_as_float((int)(v.y & 0xffff0000u));
                }
            }
            for (; j + 16 <= take; j += 16) {
                #pragma unroll
                for (int u = 0; u < 4; u++) {
                    int o = __shfl(nb, j + u * 4 + grp);
                    uint2 v = *(const uint2*)(xwb + o + l16 * 8);
                    ax[u] += __int_as_float((int)(v.x << 16));
                    ay[u] += __int_as_float((int)(v.x & 0xffff0000u));
                    az[u] += __int_as_float((int)(v.y << 16));
                    aw[u] += __int_as_float((int)(v.y & 0xffff0000u));
                }
            }
            for (; j < take; j += 4) {
                int e = j + grp;
                int o = __shfl(nb, min(e, take - 1));
                if (e < take) {
                    uint2 v = *(const uint2*)(xwb + o + l16 * 8);
                    ax[0] += __int_as_float((int)(v.x << 16));
                    ay[0] += __int_as_float((int)(v.x & 0xffff0000u));
                    az[0] += __int_as_float((int)(v.y << 16));
                    aw[0] += __int_as_float((int)(v.y & 0xffff0000u));
                }
            }
            base += take; rem -= take;
        }
        float X = ((ax[0] + ax[1]) + (ax[2] + ax[3])) + ((ax[4] + ax[5]) + (ax[6] + ax[7]));
        float Y = ((ay[0] + ay[1]) + (ay[2] + ay[3])) + ((ay[4] + ay[5]) + (ay[6] + ay[7]));
        float Z = ((az[0] + az[1]) + (az[2] + az[3])) + ((az[4] + az[5]) + (az[6] + az[7]));
        float W = ((aw[0] + aw[1]) + (aw[2] + aw[3])) + ((aw[4] + aw[5]) + (aw[6] + aw[7]));
        X += __shfl_xor(X, 16); X += __shfl_xor(X, 32);
        Y += __shfl_xor(Y, 16); Y += __shfl_xor(Y, 32);
        Z += __shfl_xor(Z, 16); Z += __shfl_xor(Z, 32);
        W += __shfl_xor(W, 16); W += __shfl_xor(W, 32);
        if (grp == 0) {
            ushort4 st;
            st.x = (unsigned short)f2bf(X);
            st.y = (unsigned short)f2bf(Y);
            st.z = (unsigned short)f2bf(Z);
            st.w = (unsigned short)f2bf(W);
            *(ushort4*)((char*)aggbuf + ((size_t)idx << 7) + l16 * 8) = st;
        }
    }
    // -------- fused pool of previous layer (reads same xw state) --------
    if (tpool >= 0) {
        int lo = wid * 64;
        if (lo < NN) {
            int hi = min(lo + 64, NN);
            float acc = 0.f;
            int curg = batch[lo];
            for (int n = lo; n < hi; n++) {
                int g = batch[n];
                if (g != curg) {
                    atomicAdd(&z[curg * (HH * LL) + tpool * HH + lane], acc);
                    acc = 0.f;
                    curg = g;
                }
                acc += __bfloat162float(xw[(size_t)n * 64 + lane]);
            }
            atomicAdd(&z[curg * (HH * LL) + tpool * HH + lane], acc);
        }
    }
}

// ---------------- MFMA Lin1: h1 = agg @ W1 + b1 ; BN partials ----------------
__global__ __launch_bounds__(256) void k_lin1(
    const __hip_bfloat16* __restrict__ aggbuf, const int* __restrict__ ccount_c,
    const short* __restrict__ wf1, const float* __restrict__ b1c,
    __hip_bfloat16* __restrict__ h1buf, float* __restrict__ bnacc) {
    int cnt = *ccount_c;
    int tiles = (cnt + 15) >> 4;
    int lane = threadIdx.x & 63;
    int wave = threadIdx.x >> 6;
    int wid = blockIdx.x * 4 + wave;
    int nwaves = gridDim.x * 4;
    int quad = lane >> 4;
    int l15 = lane & 15;

    bf16x8 wb[8];
    #pragma unroll
    for (int f = 0; f < 8; f++)
        wb[f] = *(const bf16x8*)(wf1 + f * 512 + lane * 8);
    float bcol[4];
    #pragma unroll
    for (int colt = 0; colt < 4; colt++) bcol[colt] = b1c[colt * 16 + l15];

    float sS[4] = {0.f, 0.f, 0.f, 0.f};
    float sQ[4] = {0.f, 0.f, 0.f, 0.f};

    for (int tile = wid; tile < tiles; tile += nwaves) {
        int tb = tile << 4;
        int row = tb + l15;
        const __hip_bfloat16* ar = aggbuf + (size_t)row * 64 + quad * 8;
        bf16x8 a0 = *(const bf16x8*)ar;
        bf16x8 a1 = *(const bf16x8*)(ar + 32);
        #pragma unroll
        for (int colt = 0; colt < 4; colt++) {
            f32x4 acc = {0.f, 0.f, 0.f, 0.f};
            acc = __builtin_amdgcn_mfma_f32_16x16x32_bf16(a0, wb[colt * 2 + 0], acc, 0, 0, 0);
            acc = __builtin_amdgcn_mfma_f32_16x16x32_bf16(a1, wb[colt * 2 + 1], acc, 0, 0, 0);
            #pragma unroll
            for (int r = 0; r < 4; r++) {
                int nrow = tb + quad * 4 + r;
                if (nrow < cnt) {
                    float s = acc[r] + bcol[colt];
                    __hip_bfloat16 hb = __float2bfloat16(s);
                    h1buf[(size_t)nrow * 64 + colt * 16 + l15] = hb;
                    float st = __bfloat162float(hb);
                    sS[colt] += st;
                    sQ[colt] += st * st;
                }
            }
        }
    }
    // reduce across quads (cols replicated in lanes l15, +16, +32, +48)
    #pragma unroll
    for (int colt = 0; colt < 4; colt++) {
        sS[colt] += __shfl_xor(sS[colt], 16); sS[colt] += __shfl_xor(sS[colt], 32);
        sQ[colt] += __shfl_xor(sQ[colt], 16); sQ[colt] += __shfl_xor(sQ[colt], 32);
    }
    if (quad == 0) {
        int slot = (blockIdx.x & (NSHADOW - 1)) * 128;
        #pragma unroll
        for (int colt = 0; colt < 4; colt++) {
            atomicAdd(&bnacc[slot + colt * 16 + l15], sS[colt]);
            atomicAdd(&bnacc[slot + 64 + colt * 16 + l15], sQ[colt]);
        }
    }
}

// ---------------- MFMA C: xw[node] = relu(bn(h1)) @ W2 + b2 ----------------
__global__ __launch_bounds__(256) void k_cmfma(
    __hip_bfloat16* __restrict__ xw, const int* __restrict__ clist_c,
    const int* __restrict__ ccount_c, const float* __restrict__ g1c,
    const float* __restrict__ be1c, const short* __restrict__ wf2,
    const float* __restrict__ b2c, const __hip_bfloat16* __restrict__ h1buf,
    const float* __restrict__ bnacc) {
    __shared__ float lds_scale[64];
    __shared__ float lds_shift[64];
    int cnt = *ccount_c;
    int tiles = (cnt + 15) >> 4;
    int lane = threadIdx.x & 63;
    int wave = threadIdx.x >> 6;
    int wid = blockIdx.x * 4 + wave;
    int nwaves = gridDim.x * 4;
    int quad = lane >> 4;
    int l15 = lane & 15;

    if (threadIdx.x < 64) {
        float s = 0.f, q = 0.f;
        #pragma unroll
        for (int sh = 0; sh < NSHADOW; sh++) {
            s += bnacc[sh * 128 + threadIdx.x];
            q += bnacc[sh * 128 + 64 + threadIdx.x];
        }
        float fc = fmaxf((float)cnt, 1.f);
        float mean = s / fc;
        float var = q / fc - mean * mean;
        float sc = g1c[threadIdx.x] * rsqrtf(var + BN_EPS);
        lds_scale[threadIdx.x] = sc;
        lds_shift[threadIdx.x] = be1c[threadIdx.x] - mean * sc;
    }
    __syncthreads();

    bf16x8 wb[8];
    #pragma unroll
    for (int f = 0; f < 8; f++)
        wb[f] = *(const bf16x8*)(wf2 + f * 512 + lane * 8);
    float bcol[4];
    #pragma unroll
    for (int colt = 0; colt < 4; colt++) bcol[colt] = b2c[colt * 16 + l15];
    float scl0[8], sft0[8], scl1[8], sft1[8];
    #pragma unroll
    for (int j = 0; j < 8; j++) {
        int ch = quad * 8 + j;
        scl0[j] = lds_scale[ch];      sft0[j] = lds_shift[ch];
        scl1[j] = lds_scale[ch + 32]; sft1[j] = lds_shift[ch + 32];
    }

    for (int tile = wid; tile < tiles; tile += nwaves) {
        int tb = tile << 4;
        int row = tb + l15;
        const __hip_bfloat16* hr = h1buf + (size_t)row * 64 + quad * 8;
        bf16x8 h0 = *(const bf16x8*)hr;
        bf16x8 h1f = *(const bf16x8*)(hr + 32);
        bf16x8 a0, a1;
        #pragma unroll
        for (int j = 0; j < 8; j++) {
            a0[j] = f2bf(fmaxf(bf2f(h0[j]) * scl0[j] + sft0[j], 0.f));
            a1[j] = f2bf(fmaxf(bf2f(h1f[j]) * scl1[j] + sft1[j], 0.f));
        }
        #pragma unroll
        for (int colt = 0; colt < 4; colt++) {
            f32x4 acc = {0.f, 0.f, 0.f, 0.f};
            acc = __builtin_amdgcn_mfma_f32_16x16x32_bf16(a0, wb[colt * 2 + 0], acc, 0, 0, 0);
            acc = __builtin_amdgcn_mfma_f32_16x16x32_bf16(a1, wb[colt * 2 + 1], acc, 0, 0, 0);
            #pragma unroll
            for (int r = 0; r < 4; r++) {
                int nrow = tb + quad * 4 + r;
                if (nrow < cnt) {
                    int node = clist_c[nrow];
                    xw[(size_t)node * 64 + colt * 16 + l15] =
                        __float2bfloat16(acc[r] + bcol[colt]);
                }
            }
        }
    }
}

// ---------------- pooling (standalone, used for last layer; R33 restored) ----
__global__ void k_pool(const __hip_bfloat16* __restrict__ xw, const int* __restrict__ batch,
                       float* __restrict__ z, int t) {
    const int CHUNK = 64;
    int lane = threadIdx.x & 63;
    int wg = (blockIdx.x * blockDim.x + threadIdx.x) >> 6;
    int lo = wg * CHUNK;
    if (lo >= NN) return;
    int hi = min(lo + CHUNK, NN);
    float acc = 0.f;
    int curg = batch[lo];
    for (int n = lo; n < hi; n++) {
        int g = batch[n];
        if (g != curg) {
            atomicAdd(&z[curg * (HH * LL) + t * HH + lane], acc);
            acc = 0.f;
            curg = g;
        }
        acc += __bfloat162float(xw[(size_t)n * 64 + lane]);
    }
    atomicAdd(&z[curg * (HH * LL) + t * HH + lane], acc);
}

// ---------------- final MLP (split for parallelism, R7-proven; R33 restored) --
__global__ __launch_bounds__(256) void k_final1(
    const float* __restrict__ z, const float* __restrict__ Wp1,
    const float* __restrict__ bp1, float* __restrict__ hbuf) {
    __shared__ float red[256];
    int g = blockIdx.x;
    int k = threadIdx.x & 63;
    int part = threadIdx.x >> 6;  // 4 parts x 48 j's
    float s = 0.f;
    #pragma unroll 8
    for (int j = part * 48; j < (part + 1) * 48; j++)
        s += z[g * (HH * LL) + j] * Wp1[j * 64 + k];
    red[threadIdx.x] = s;
    __syncthreads();
    if (part == 0)
        hbuf[g * 64 + k] = red[k] + red[64 + k] + red[128 + k] + red[192 + k] + bp1[k];
}

__global__ __launch_bounds__(256) void k_final2(
    const float* __restrict__ hbuf, const float* __restrict__ gp,
    const float* __restrict__ bep, const float* __restrict__ Wp2,
    const float* __restrict__ bp2, float* __restrict__ out) {
    __shared__ float lds[64 * 64];
    __shared__ float sscale[64];
    __shared__ float sshift[64];
    int tid = threadIdx.x;
    for (int i = tid; i < 64 * 64; i += 256) lds[i] = hbuf[i];
    __syncthreads();
    if (tid < 64) {
        float s = 0.f, q = 0.f;
        for (int g = 0; g < 64; g++) { float v = lds[g * 64 + tid]; s += v; q += v * v; }
        float mean = s / 64.f;
        float var = q / 64.f - mean * mean;
        float sc = gp[tid] * rsqrtf(var + BN_EPS);
        sscale[tid] = sc;
        sshift[tid] = bep[tid] - mean * sc;
    }
    __syncthreads();
    for (int i = tid; i < 64 * 64; i += 256) {
        int k = i & 63;
        lds[i] = fmaxf(lds[i] * sscale[k] + sshift[k], 0.f);
    }
    __syncthreads();
    for (int i = tid; i < 64 * 64; i += 256) {
        int g = i >> 6, o = i & 63;
        float s = bp2[o];
        #pragma unroll 8
        for (int k = 0; k < 64; k++) s += lds[g * 64 + k] * Wp2[k * 64 + o];
        out[g * 64 + o] = s;
    }
}

// ---------------- launch ----------------
extern "C" void kernel_launch(void* const* d_in, const int* in_sizes, int n_in,
                              void* d_out, int out_size, void* d_ws, size_t ws_size,
                              hipStream_t stream) {
    const float* x_in = (const float*)d_in[0];
    const int* labels = (const int*)d_in[1];
    const int* esrc = (const int*)d_in[2];
    const int* edst = esrc + EE;
    const int* batch = (const int*)d_in[3];
    const float* W1 = (const float*)d_in[4];
    const float* b1 = (const float*)d_in[5];
    const float* g1 = (const float*)d_in[6];
    const float* be1 = (const float*)d_in[7];
    const float* W2 = (const float*)d_in[8];
    const float* b2 = (const float*)d_in[9];
    const float* Wp1 = (const float*)d_in[10];
    const float* bp1 = (const float*)d_in[11];
    const float* gp = (const float*)d_in[12];
    const float* bep = (const float*)d_in[13];
    const float* Wp2 = (const float*)d_in[14];
    const float* bp2 = (const float*)d_in[15];
    float* out = (float*)d_out;

    char* p = (char*)d_ws;
    auto carve = [&](size_t bytes) -> void* {
        void* r = (void*)p;
        p += (bytes + 255) & ~(size_t)255;
        return r;
    };
    // ---- zeroed region (one memset) ----
    float* bnacc = (float*)carve((size_t)LL * CC * NSHADOW * 128 * 4);
    float* z     = (float*)carve((size_t)GG * HH * LL * 4);
    int*   deg   = (int*)carve((size_t)NN * 4);
    size_t zero_bytes = (size_t)(p - (char*)d_ws);
    // ---- rest ----
    int*   ccount  = (int*)carve(CC * 4);
    int*   blockcnt= (int*)carve((size_t)CC * SBLK * 4);
    int*   coffs   = (int*)carve((size_t)CC * SBLK * 4);
    int*   dpart   = (int*)carve((size_t)SBLK * 4);
    int*   dbase   = (int*)carve((size_t)SBLK * 4);
    __hip_bfloat16* xw     = (__hip_bfloat16*)carve((size_t)NN * 64 * 2);
    __hip_bfloat16* aggbuf = (__hip_bfloat16*)carve((size_t)NN * 64 * 2);
    __hip_bfloat16* h1buf  = (__hip_bfloat16*)carve((size_t)NN * 64 * 2);
    short* wf      = (short*)carve((size_t)24 * 4096 * 2);
    float* hbuf    = (float*)carve((size_t)GG * 64 * 4);
    int*   rowptr  = (int*)carve((size_t)(NN + 1) * 4);
    int*   cursor  = (int*)carve((size_t)NN * 4);
    int*   adj     = (int*)carve((size_t)EE * 4);
    int*   clist   = (int*)carve((size_t)CC * NN * 4);

    hipMemsetAsync(d_ws, 0, zero_bytes, stream);

    k_deghist<<<ECHUNKS, 256, 0, stream>>>(edst, deg, labels, blockcnt, x_in, xw, W1, W2, wf);
    k_scancombo<<<SBLK + 1, 256, 0, stream>>>(deg, rowptr, dpart, blockcnt, coffs, ccount);
    k_dscan2<<<1, 256, 0, stream>>>(dpart, dbase, rowptr);
    k_cfill_dscan3<<<SBLK, 256, 0, stream>>>(rowptr, dbase, cursor, labels, coffs, clist);
    k_fill<<<ECHUNKS * 8, 256, 0, stream>>>(esrc, edst, cursor, adj);

    for (int t = 0; t < LL; t++) {
        for (int c = 0; c < CC; c++) {
            int tc = t * CC + c;
            int tpool = (c == 0) ? (t - 1) : -1;  // fuse previous layer's pool into gather
            k_gather<<<GIN_BLOCKS, 256, 0, stream>>>(
                xw, adj, rowptr, clist + c * NN, ccount + c, aggbuf, batch, z, tpool);
            k_lin1<<<MM_BLOCKS, 256, 0, stream>>>(
                aggbuf, ccount + c, wf + (size_t)tc * 4096, b1 + (size_t)tc * 64,
                h1buf, bnacc + (size_t)tc * NSHADOW * 128);
            k_cmfma<<<MM_BLOCKS, 256, 0, stream>>>(
                xw, clist + c * NN, ccount + c,
                g1 + (size_t)tc * 64, be1 + (size_t)tc * 64,
                wf + (size_t)(12 + tc) * 4096, b2 + (size_t)tc * 64,
                h1buf, bnacc + (size_t)tc * NSHADOW * 128);
        }
    }
    // last layer's pool (standalone, R33 restored)
    {
        int pool_waves = (NN + 63) / 64;
        int pool_blocks = (pool_waves * 64 + 255) / 256;
        k_pool<<<pool_blocks, 256, 0, stream>>>(xw, batch, z, LL - 1);
    }
    k_final1<<<GG, 256, 0, stream>>>(z, Wp1, bp1, hbuf);
    k_final2<<<1, 256, 0, stream>>>(hbuf, gp, bep, Wp2, bp2, out);
}